// Round 1
// baseline (263.823 us; speedup 1.0000x reference)
//
#include <hip/hip_runtime.h>

#define NUM_NODES 50000
#define WINDOW 8
#define DIM 256
#define BATCH 8192

// -------- kernel 1: per-node occurrence count (order-independent, deterministic) ----
__global__ void count_kernel(const int* __restrict__ idx, int* __restrict__ count) {
    int bi = blockIdx.x * blockDim.x + threadIdx.x;
    if (bi < BATCH) atomicAdd(&count[idx[bi]], 1);
}

// -------- kernel 2: rank + slot + winner code ----------------------------------------
// rank[bi] = #{j < bi : idx[j]==idx[bi]}   (only needed when count>1, ~1% of elements)
// slot = (ptr[node] + rank) % 8 ; winner iff rank >= count-8 (last writer per slot wins)
__global__ void rank_kernel(const int* __restrict__ idx, const int* __restrict__ ptr,
                            const int* __restrict__ count, int* __restrict__ slotcode) {
    __shared__ int sidx[BATCH];     // 32 KiB
    __shared__ int anyneed;
    int tid = threadIdx.x;
    int bi  = blockIdx.x * blockDim.x + tid;

    int node = idx[bi];
    int c    = count[node];
    bool need = (c > 1);

    if (tid == 0) anyneed = 0;
    __syncthreads();
    if (need) anyneed = 1;          // benign race, resolved by next barrier
    __syncthreads();

    if (anyneed) {                  // stage full idx array in LDS only if someone scans
        for (int j = tid; j < BATCH; j += blockDim.x) sidx[j] = idx[j];
        __syncthreads();
    }

    int rank = 0;
    if (need) {
        for (int j = 0; j < bi; ++j) rank += (sidx[j] == node);
    }

    int slot = (ptr[node] + rank) & (WINDOW - 1);   // ptr >= 0
    int win  = (rank >= c - WINDOW);
    slotcode[bi] = win ? (node * WINDOW + slot) : -1;
}

// -------- kernel 3: scatter winners into the (already copied) bank + timestamps ------
__global__ void scatter_kernel(const int* __restrict__ slotcode,
                               const float* __restrict__ nrep,
                               const float* __restrict__ t,
                               float* __restrict__ out_bank,
                               float* __restrict__ out_ts) {
    int bi   = blockIdx.x;
    int code = slotcode[bi];
    if (code < 0) return;
    int lane = threadIdx.x;         // 64 lanes x float4 = 256 floats
    const float4* src = (const float4*)(nrep + (size_t)bi * DIM);
    float4*       dst = (float4*)(out_bank + (size_t)code * DIM);
    dst[lane] = src[lane];
    if (lane == 0) out_ts[code] = t[bi];
}

// -------- kernel 4: ptr_new = float(ptr + count) -------------------------------------
__global__ void ptr_kernel(const int* __restrict__ ptr, const int* __restrict__ count,
                           float* __restrict__ out_ptr) {
    int n = blockIdx.x * blockDim.x + threadIdx.x;
    if (n < NUM_NODES) out_ptr[n] = (float)(ptr[n] + count[n]);
}

extern "C" void kernel_launch(void* const* d_in, const int* in_sizes, int n_in,
                              void* d_out, int out_size, void* d_ws, size_t ws_size,
                              hipStream_t stream) {
    const float* bank       = (const float*)d_in[0];
    const float* timestamps = (const float*)d_in[1];
    const float* nrep       = (const float*)d_in[2];
    const float* t          = (const float*)d_in[3];
    const int*   ptr        = (const int*)  d_in[4];
    const int*   idx        = (const int*)  d_in[5];

    float* out_bank = (float*)d_out;
    float* out_ts   = out_bank + (size_t)NUM_NODES * WINDOW * DIM;
    float* out_ptr  = out_ts   + (size_t)NUM_NODES * WINDOW;

    int* count    = (int*)d_ws;            // NUM_NODES ints
    int* slotcode = count + NUM_NODES;     // BATCH ints

    // zero the per-node counters (workspace is NOT re-poisoned between replays)
    hipMemsetAsync(count, 0, NUM_NODES * sizeof(int), stream);

    count_kernel<<<(BATCH + 255) / 256, 256, 0, stream>>>(idx, count);
    rank_kernel<<<BATCH / 256, 256, 0, stream>>>(idx, ptr, count, slotcode);

    // bulk copy: bank (409.6 MB) + timestamps (1.6 MB) — the HBM-bound floor
    hipMemcpyAsync(out_bank, bank,
                   (size_t)NUM_NODES * WINDOW * DIM * sizeof(float),
                   hipMemcpyDeviceToDevice, stream);
    hipMemcpyAsync(out_ts, timestamps,
                   (size_t)NUM_NODES * WINDOW * sizeof(float),
                   hipMemcpyDeviceToDevice, stream);

    // overwrite the scattered rows (runs after copies in stream order)
    scatter_kernel<<<BATCH, 64, 0, stream>>>(slotcode, nrep, t, out_bank, out_ts);
    ptr_kernel<<<(NUM_NODES + 255) / 256, 256, 0, stream>>>(ptr, count, out_ptr);
}

// Round 2
// 241.902 us; speedup vs baseline: 1.0906x; 1.0906x over previous
//
#include <hip/hip_runtime.h>

#define NUM_NODES 50000
#define WINDOW 8
#define DIM 256
#define BATCH 8192

// -------- kernel 1: per-node occurrence count (order-independent, deterministic) ----
__global__ void count_kernel(const int* __restrict__ idx, int* __restrict__ count) {
    int bi = blockIdx.x * blockDim.x + threadIdx.x;
    if (bi < BATCH) atomicAdd(&count[idx[bi]], 1);
}

// -------- kernel 2: rank + winner map -------------------------------------------------
// rank[bi] = #{j < bi : idx[j]==idx[bi]}   (only needed when count>1, ~1-2% of elements)
// slot = (ptr[node] + rank) % 8 ; winner iff rank >= count-8 (the last writer per slot).
// Winners are the last min(c,8) occurrences -> distinct slots -> unique writer per code.
__global__ void rank_kernel(const int* __restrict__ idx, const int* __restrict__ ptr,
                            const int* __restrict__ count, int* __restrict__ winner) {
    __shared__ int sidx[BATCH];     // 32 KiB
    __shared__ int anyneed;
    int tid = threadIdx.x;
    int bi  = blockIdx.x * blockDim.x + tid;

    int node = idx[bi];
    int c    = count[node];
    bool need = (c > 1);

    if (tid == 0) anyneed = 0;
    __syncthreads();
    if (need) anyneed = 1;          // benign race, resolved by next barrier
    __syncthreads();

    if (anyneed) {                  // stage full idx array in LDS only if someone scans
        for (int j = tid; j < BATCH; j += blockDim.x) sidx[j] = idx[j];
        __syncthreads();
    }

    int rank = 0;
    if (need) {
        for (int j = 0; j < bi; ++j) rank += (sidx[j] == node);
    }

    if (rank >= c - WINDOW) {       // winner
        int slot = (ptr[node] + rank) & (WINDOW - 1);   // ptr >= 0
        winner[node * WINDOW + slot] = bi;
    }
}

// -------- kernel 3: fused copy + scatter-select (the HBM-bound pass) -----------------
// One float4 per thread-iteration over the whole bank (25.6M float4s). Row's source is
// bank unless winner[row] >= 0, then neighbor_repr[winner]. Lane 0 of each row also
// resolves the timestamp.
__global__ void __launch_bounds__(256)
fused_copy_kernel(const float4* __restrict__ bank4,
                  const float*  __restrict__ timestamps,
                  const float4* __restrict__ nrep4,
                  const float*  __restrict__ t,
                  const int*    __restrict__ winner,
                  float4* __restrict__ out_bank4,
                  float*  __restrict__ out_ts) {
    const long total = (long)NUM_NODES * WINDOW * (DIM / 4);   // 25.6M float4
    const long nth   = (long)gridDim.x * blockDim.x;
    for (long i = (long)blockIdx.x * blockDim.x + threadIdx.x; i < total; i += nth) {
        int  row = (int)(i >> 6);          // 64 float4s per row
        int  w   = winner[row];
        float4 v = (w >= 0) ? nrep4[(long)w * (DIM / 4) + (i & 63)] : bank4[i];
        out_bank4[i] = v;
        if ((i & 63) == 0)
            out_ts[row] = (w >= 0) ? t[w] : timestamps[row];
    }
}

// -------- kernel 4: ptr_new = float(ptr + count) -------------------------------------
__global__ void ptr_kernel(const int* __restrict__ ptr, const int* __restrict__ count,
                           float* __restrict__ out_ptr) {
    int n = blockIdx.x * blockDim.x + threadIdx.x;
    if (n < NUM_NODES) out_ptr[n] = (float)(ptr[n] + count[n]);
}

extern "C" void kernel_launch(void* const* d_in, const int* in_sizes, int n_in,
                              void* d_out, int out_size, void* d_ws, size_t ws_size,
                              hipStream_t stream) {
    const float* bank       = (const float*)d_in[0];
    const float* timestamps = (const float*)d_in[1];
    const float* nrep       = (const float*)d_in[2];
    const float* t          = (const float*)d_in[3];
    const int*   ptr        = (const int*)  d_in[4];
    const int*   idx        = (const int*)  d_in[5];

    float* out_bank = (float*)d_out;
    float* out_ts   = out_bank + (size_t)NUM_NODES * WINDOW * DIM;
    float* out_ptr  = out_ts   + (size_t)NUM_NODES * WINDOW;

    int* count  = (int*)d_ws;              // NUM_NODES ints
    int* winner = count + NUM_NODES;       // NUM_NODES*WINDOW ints (1.6 MB)

    // workspace is NOT re-poisoned between replays: re-init both arrays every call
    hipMemsetAsync(count, 0, NUM_NODES * sizeof(int), stream);
    hipMemsetAsync(winner, 0xFF, (size_t)NUM_NODES * WINDOW * sizeof(int), stream); // -1

    count_kernel<<<(BATCH + 255) / 256, 256, 0, stream>>>(idx, count);
    rank_kernel<<<BATCH / 256, 256, 0, stream>>>(idx, ptr, count, winner);

    fused_copy_kernel<<<2048, 256, 0, stream>>>(
        (const float4*)bank, timestamps, (const float4*)nrep, t, winner,
        (float4*)out_bank, out_ts);

    ptr_kernel<<<(NUM_NODES + 255) / 256, 256, 0, stream>>>(ptr, count, out_ptr);
}